// Round 1
// baseline (214.341 us; speedup 1.0000x reference)
//
#include <hip/hip_runtime.h>

#define DIM 768
#define TD 2304          // 3*DIM
#define NB 8
#define NS 4096
#define NE 6

// ws layout (floats):
//   [0, 27648)            Qcat [2304][12]  : [0..5]=Q coefs (M1+M2+sync), [6..11]=P coefs (M2)
//   [27648, 27648+18432)  colsum [8][2304]
//   [46080, 46080+48)     constb [8][6]

// ---------------- kernel 0: fold coefficient matrices ----------------
__global__ __launch_bounds__(256) void k_fold(
    const float* __restrict__ Wspat, const float* __restrict__ Wtemp,
    const float* __restrict__ Wsync, const float* __restrict__ Wroute,
    float* __restrict__ Qcat)
{
    __shared__ float lwr[288 * NE];
    for (int i = threadIdx.x; i < 288 * NE; i += 256) lwr[i] = Wroute[i];
    __syncthreads();
    const int d = blockIdx.x * 256 + threadIdx.x;   // grid is exactly 2304 threads

    float p[NE] = {0, 0, 0, 0, 0, 0};
    for (int o = 0; o < 64; ++o) {
        const float w = Wtemp[d * 64 + o];
        #pragma unroll
        for (int e = 0; e < NE; ++e) p[e] += w * lwr[(128 + o) * NE + e];
    }
    float qq[NE];
    #pragma unroll
    for (int e = 0; e < NE; ++e) qq[e] = p[e];
    for (int o = 0; o < 128; ++o) {
        const float w = Wspat[d * 128 + o];
        #pragma unroll
        for (int e = 0; e < NE; ++e) qq[e] += w * lwr[o * NE + e];
    }
    const int st = d / DIM, dd = d - st * DIM;
    if (st != 0) {
        const float sg = (st == 1) ? 1.f : -1.f;
        for (int o = 0; o < 32; ++o) {
            const float w = sg * Wsync[dd * 32 + o];
            #pragma unroll
            for (int e = 0; e < NE; ++e) qq[e] += w * lwr[(192 + o) * NE + e];
        }
    }
    #pragma unroll
    for (int e = 0; e < NE; ++e) { Qcat[d * 12 + e] = qq[e]; Qcat[d * 12 + 6 + e] = p[e]; }
}

// ---------------- kernel 1: main streaming pass ----------------
// 512 blocks = 8 b * 64 row-chunks of 64 rows. 256 threads = 4 waves,
// wave q owns d-quarter [q*576, (q+1)*576), lane = local row.
__global__ __launch_bounds__(256, 2) void k_main(
    const float* __restrict__ xt, const float* __restrict__ xa, const float* __restrict__ xv,
    const float* __restrict__ Qcat, float* __restrict__ colsum, float* __restrict__ out)
{
    __shared__ float sx[4 * 64 * 33];      // x tile: [quarter][row][32+1 pad]  (33.0 KB)
    __shared__ float scoef[4 * 32 * 12];   // coef chunk: [quarter][c][12]      (6.0 KB)
    __shared__ float qacc[64 * NE];
    __shared__ float pacc[65 * NE];        // slot 0 = boundary row p

    const int t   = threadIdx.x;
    const int q   = t >> 6;                // quarter == wave
    const int l   = t & 63;                // lane == local row
    const int bb  = blockIdx.x >> 6;
    const int rb0 = (blockIdx.x & 63) << 6;

    const float* Xs[3] = { xt, xa, xv };

    for (int i = t; i < 64 * NE; i += 256) qacc[i] = 0.f;
    for (int i = t; i < 65 * NE; i += 256) pacc[i] = 0.f;
    __syncthreads();

    // staging geometry: lane stages 8 float4 with fixed column-quad c4 = l&7
    const int c4  = l & 7;
    const int r0s = l >> 3;
    const int xrowbase = (bb * NS + rb0) * DIM;

    float4 hx[8];
    float4 hc0, hc1;

    auto issue_loads = [&](int j) {
        const int D0 = q * 576 + j * 32;           // chunks never straddle streams (768%32==0)
        const int st = D0 / DIM, dd0 = D0 - st * DIM;
        const float* Xp = Xs[st] + xrowbase + dd0 + 4 * c4;
        #pragma unroll
        for (int k = 0; k < 8; ++k)
            hx[k] = *(const float4*)(Xp + (r0s + 8 * k) * DIM);
        {
            const int g = t, qg = g / 96, kk = g - qg * 96;
            hc0 = *(const float4*)(Qcat + ((qg * 576 + j * 32) * 3 + kk) * 4);
        }
        if (t < 128) {
            const int g = 256 + t, qg = g / 96, kk = g - qg * 96;
            hc1 = *(const float4*)(Qcat + ((qg * 576 + j * 32) * 3 + kk) * 4);
        }
    };

    auto write_stage = [&](int j) {
        #pragma unroll
        for (int k = 0; k < 8; ++k) {               // scalar writes keep stride-33 layout
            float* dst = &sx[(q * 64 + r0s + 8 * k) * 33 + 4 * c4];
            dst[0] = hx[k].x; dst[1] = hx[k].y; dst[2] = hx[k].z; dst[3] = hx[k].w;
        }
        {
            const int g = t, qg = g / 96, kk = g - qg * 96;
            *(float4*)&scoef[qg * 384 + kk * 4] = hc0;
        }
        if (t < 128) {
            const int g = 256 + t, qg = g / 96, kk = g - qg * 96;
            *(float4*)&scoef[qg * 384 + kk * 4] = hc1;
        }
        // column-sum flush: lane's 8 rows, 4 fixed columns
        float cs0 = 0, cs1 = 0, cs2 = 0, cs3 = 0;
        #pragma unroll
        for (int k = 0; k < 8; ++k) { cs0 += hx[k].x; cs1 += hx[k].y; cs2 += hx[k].z; cs3 += hx[k].w; }
        #pragma unroll
        for (int m = 8; m < 64; m <<= 1) {
            cs0 += __shfl_xor(cs0, m, 64);
            cs1 += __shfl_xor(cs1, m, 64);
            cs2 += __shfl_xor(cs2, m, 64);
            cs3 += __shfl_xor(cs3, m, 64);
        }
        if (l < 8) {
            float* cp = &colsum[bb * TD + q * 576 + j * 32 + 4 * l];
            atomicAdd(cp + 0, cs0);
            atomicAdd(cp + 1, cs1);
            atomicAdd(cp + 2, cs2);
            atomicAdd(cp + 3, cs3);
        }
    };

    issue_loads(0);

    // boundary prologue (overlapped with first stage loads): p of row rb0-1 (or rb0 at s=0)
    {
        const int rprev = (rb0 == 0) ? 0 : (rb0 - 1);
        const int base = (bb * NS + rprev) * DIM;
        float pb[NE] = {0, 0, 0, 0, 0, 0};
        const int d0 = q * 576 + l * 9;
        for (int k = 0; k < 9; ++k) {
            const int d = d0 + k;
            const int st = d / DIM, dd = d - st * DIM;
            const float xvv = Xs[st][base + dd];
            #pragma unroll
            for (int e = 0; e < NE; ++e) pb[e] += xvv * Qcat[d * 12 + 6 + e];
        }
        #pragma unroll
        for (int m = 1; m < 64; m <<= 1) {
            #pragma unroll
            for (int e = 0; e < NE; ++e) pb[e] += __shfl_xor(pb[e], m, 64);
        }
        if (l == 0) {
            #pragma unroll
            for (int e = 0; e < NE; ++e) atomicAdd(&pacc[e], pb[e]);
        }
    }

    write_stage(0);
    __syncthreads();

    float qv[NE] = {0, 0, 0, 0, 0, 0};
    float pv[NE] = {0, 0, 0, 0, 0, 0};

    for (int j = 0; j < 18; ++j) {
        if (j < 17) issue_loads(j + 1);            // loads in flight during compute
        const float* xrow = &sx[(q * 64 + l) * 33];
        const float* cf   = &scoef[q * 384];
        #pragma unroll 8
        for (int c = 0; c < 32; ++c) {
            const float x = xrow[c];
            const float4 a  = *(const float4*)(cf + c * 12);
            const float4 b2 = *(const float4*)(cf + c * 12 + 4);
            const float4 c2 = *(const float4*)(cf + c * 12 + 8);
            qv[0] += x * a.x;  qv[1] += x * a.y;  qv[2] += x * a.z;  qv[3] += x * a.w;
            qv[4] += x * b2.x; qv[5] += x * b2.y;
            pv[0] += x * b2.z; pv[1] += x * b2.w;
            pv[2] += x * c2.x; pv[3] += x * c2.y; pv[4] += x * c2.z; pv[5] += x * c2.w;
        }
        __syncthreads();                            // everyone done reading tile j
        if (j < 17) { write_stage(j + 1); __syncthreads(); }
    }

    #pragma unroll
    for (int e = 0; e < NE; ++e) atomicAdd(&qacc[l * NE + e], qv[e]);
    #pragma unroll
    for (int e = 0; e < NE; ++e) atomicAdd(&pacc[(l + 1) * NE + e], pv[e]);
    __syncthreads();

    if (t < 64) {
        float* op = out + (bb * NS + rb0 + t) * NE;
        #pragma unroll
        for (int e = 0; e < NE; ++e) op[e] = qacc[t * NE + e] - pacc[t * NE + e];
    }
}

// ---------------- kernel 2: per-batch global constant ----------------
__global__ __launch_bounds__(256) void k_const(
    const float* __restrict__ xt, const float* __restrict__ xa, const float* __restrict__ xv,
    const float* __restrict__ colsum,
    const float* __restrict__ Wspat, const float* __restrict__ bspat,
    const float* __restrict__ Wtemp, const float* __restrict__ btemp,
    const float* __restrict__ Wsync, const float* __restrict__ bsync,
    const float* __restrict__ Wglob, const float* __restrict__ bglob,
    const float* __restrict__ Wroute, const float* __restrict__ broute,
    float* __restrict__ constb)
{
    __shared__ float scs[TD];     // column means
    __shared__ float sdiff[TD];   // mean of deltas = (x_last - x_first)/S
    __shared__ float gs[224];
    __shared__ float gv[64];
    const int b = blockIdx.x, t = threadIdx.x;
    const float* Xs[3] = { xt, xa, xv };
    const float inv = 1.f / 4096.f;
    for (int i = t; i < TD; i += 256) {
        scs[i] = colsum[b * TD + i] * inv;
        const int st = i / DIM, dd = i - st * DIM;
        const float* Xp = Xs[st] + b * NS * DIM;
        sdiff[i] = (Xp[(NS - 1) * DIM + dd] - Xp[dd]) * inv;
    }
    __syncthreads();
    if (t < 128) {
        float acc = bspat[t];
        for (int f = 0; f < TD; ++f) acc += scs[f] * Wspat[f * 128 + t];
        gs[t] = acc;
    } else if (t < 192) {
        const int o = t - 128;
        float acc = btemp[o];
        for (int f = 0; f < TD; ++f) acc += sdiff[f] * Wtemp[f * 64 + o];
        gs[t] = acc;
    } else if (t < 224) {
        const int o = t - 192;
        float acc = bsync[o];
        for (int dd = 0; dd < DIM; ++dd) acc += (scs[DIM + dd] - scs[2 * DIM + dd]) * Wsync[dd * 32 + o];
        gs[t] = acc;
    }
    __syncthreads();
    if (t < 64) {
        float acc = bglob[t];
        for (int f = 0; f < 224; ++f) acc += gs[f] * Wglob[f * 64 + t];
        gv[t] = acc;
    }
    __syncthreads();
    if (t < NE) {
        float acc = broute[t];
        for (int o = 0; o < 64; ++o)  acc += gv[o]    * Wroute[(224 + o) * NE + t];
        for (int o = 0; o < 128; ++o) acc += bspat[o] * Wroute[o * NE + t];
        for (int o = 0; o < 64; ++o)  acc += btemp[o] * Wroute[(128 + o) * NE + t];
        for (int o = 0; o < 32; ++o)  acc += bsync[o] * Wroute[(192 + o) * NE + t];
        constb[b * NE + t] = acc;
    }
}

// ---------------- kernel 3: broadcast-add const ----------------
__global__ __launch_bounds__(256) void k_add(float* __restrict__ out, const float* __restrict__ constb)
{
    const int i = blockIdx.x * 256 + threadIdx.x;   // 768*256 == 196608 exact
    const int row = i / NE;
    const int e = i - row * NE;
    const int b = row >> 12;
    out[i] += constb[b * NE + e];
}

extern "C" void kernel_launch(void* const* d_in, const int* in_sizes, int n_in,
                              void* d_out, int out_size, void* d_ws, size_t ws_size,
                              hipStream_t stream)
{
    const float* xt     = (const float*)d_in[0];
    const float* xa     = (const float*)d_in[1];
    const float* xv     = (const float*)d_in[2];
    const float* Wspat  = (const float*)d_in[3];
    const float* bspat  = (const float*)d_in[4];
    const float* Wtemp  = (const float*)d_in[5];
    const float* btemp  = (const float*)d_in[6];
    const float* Wsync  = (const float*)d_in[7];
    const float* bsync  = (const float*)d_in[8];
    const float* Wglob  = (const float*)d_in[9];
    const float* bglob  = (const float*)d_in[10];
    const float* Wroute = (const float*)d_in[11];
    const float* broute = (const float*)d_in[12];
    float* out = (float*)d_out;

    float* Qcat   = (float*)d_ws;
    float* colsum = Qcat + TD * 12;
    float* constb = colsum + NB * TD;

    hipMemsetAsync(colsum, 0, NB * TD * sizeof(float), stream);
    k_fold<<<9, 256, 0, stream>>>(Wspat, Wtemp, Wsync, Wroute, Qcat);
    k_main<<<512, 256, 0, stream>>>(xt, xa, xv, Qcat, colsum, out);
    k_const<<<8, 256, 0, stream>>>(xt, xa, xv, colsum, Wspat, bspat, Wtemp, btemp,
                                   Wsync, bsync, Wglob, bglob, Wroute, broute, constb);
    k_add<<<768, 256, 0, stream>>>(out, constb);
}